// Round 7
// baseline (768.724 us; speedup 1.0000x reference)
//
#include <hip/hip_runtime.h>
#include <hip/hip_bf16.h>

#define NF   128
#define HCC  512
#define FFND 256
#define NEG  0.2f
#define EPSLN 1e-5f

typedef __attribute__((ext_vector_type(8))) short short8;
typedef __attribute__((ext_vector_type(4))) float f32x4;

// ---------- tiny init / prep ----------
__global__ void init_gw_kernel(const float* __restrict__ gate, float* __restrict__ gw) {
  if (threadIdx.x == 0 && blockIdx.x == 0) {
    float a = gate[0], b = gate[1], c = gate[2], d = gate[3];
    float m = fmaxf(fmaxf(a, b), fmaxf(c, d));
    float e0 = __expf(a - m), e1 = __expf(b - m), e2 = __expf(c - m), e3 = __expf(d - m);
    float s = e0 + e1 + e2 + e3;
    gw[0] = e0 / s; gw[1] = e1 / s; gw[2] = e2 / s; gw[3] = e3 / s;
  }
}

__global__ void init_all_kernel(float* __restrict__ denom, int* __restrict__ sorted,
                                int ndenom, int nsorted) {
  int i = blockIdx.x * 256 + threadIdx.x;
  if (i < ndenom)  denom[i] = 0.f;
  if (i < nsorted) sorted[i] = -1;
}

__global__ void init_hmsg_kernel(const float* __restrict__ gw, const float* __restrict__ bias,
                                 float* __restrict__ hmsg, int total) {
  int i = blockIdx.x * 256 + threadIdx.x;
  if (i < total) {
    int c = i & 127;
    hmsg[i] = gw[0]*bias[c] + gw[1]*bias[128+c] + gw[2]*bias[256+c] + gw[3]*bias[384+c];
  }
}

// fp32 [batch][rows][cols] -> bf16 [batch][cols][rows]
__global__ void transpose_bf16_kernel(const float* __restrict__ in, __hip_bfloat16* __restrict__ out,
                                      int rows, int cols, int total) {
  int i = blockIdx.x * 256 + threadIdx.x;
  if (i >= total) return;
  int per = rows * cols;
  int b = i / per, rem = i % per;
  int rr = rem / cols, cc = rem % cols;
  out[(size_t)b * per + (size_t)cc * rows + rr] = __float2bfloat16(in[i]);
}

__global__ void cvt_bf16_kernel(const float* __restrict__ in, __hip_bfloat16* __restrict__ out, int n) {
  int i4 = (blockIdx.x * 256 + threadIdx.x) * 4;
  if (i4 >= n) return;
  float4 v = *(const float4*)(in + i4);
  out[i4]     = __float2bfloat16(v.x);
  out[i4 + 1] = __float2bfloat16(v.y);
  out[i4 + 2] = __float2bfloat16(v.z);
  out[i4 + 3] = __float2bfloat16(v.w);
}

// bias_comb[r][512] = b_r[r] + rel_emb[r] @ W_e[r][16:24]
__global__ void prep_bias_kernel(const float* __restrict__ b_r, const float* __restrict__ rel_emb,
                                 const float* __restrict__ W_e, float* __restrict__ bias_comb) {
  int i = blockIdx.x * 256 + threadIdx.x;
  if (i >= 4 * 512) return;
  int col = i & 511, r = i >> 9;
  float v = b_r[i];
#pragma unroll
  for (int j = 0; j < 8; ++j)
    v += rel_emb[r * 8 + j] * W_e[(size_t)r * 24 * 512 + (size_t)(16 + j) * 512 + col];
  bias_comb[i] = v;
}

// ---------- atomic-free counting sort by relation ----------
__global__ void blockhist_kernel(const int* __restrict__ etype, int* __restrict__ blockCnt, int E) {
  __shared__ int wcnt[4][4];
  int i = blockIdx.x * 256 + threadIdx.x;
  int rt = (i < E) ? etype[i] : -1;
  int wave = threadIdx.x >> 6, lane = threadIdx.x & 63;
#pragma unroll
  for (int r = 0; r < 4; ++r) {
    unsigned long long m = __ballot(rt == r);
    if (lane == 0) wcnt[wave][r] = __popcll(m);
  }
  __syncthreads();
  if (threadIdx.x < 4) {
    int r = threadIdx.x;
    blockCnt[blockIdx.x * 4 + r] = wcnt[0][r] + wcnt[1][r] + wcnt[2][r] + wcnt[3][r];
  }
}

__global__ void scan_kernel(const int* __restrict__ blockCnt, int* __restrict__ blockBase,
                            int* __restrict__ offs, int nBlocks) {
  __shared__ int lds[256];
  __shared__ int offs_s[5];
  __shared__ int tot_s[4];
  int t = threadIdx.x;
  int C = (nBlocks + 255) / 256;
  for (int r = 0; r < 4; ++r) {
    int s = 0;
    for (int b = t; b < nBlocks; b += 256) s += blockCnt[b * 4 + r];
    lds[t] = s;
    __syncthreads();
    for (int o = 128; o > 0; o >>= 1) {
      if (t < o) lds[t] += lds[t + o];
      __syncthreads();
    }
    if (t == 0) tot_s[r] = lds[0];
    __syncthreads();
  }
  if (t == 0) {
    int o = 0;
    offs_s[0] = 0;
    for (int r = 0; r < 4; ++r) { o += ((tot_s[r] + 63) >> 6) << 6; offs_s[r + 1] = o; }
    for (int r = 0; r < 5; ++r) offs[r] = offs_s[r];
  }
  __syncthreads();
  for (int r = 0; r < 4; ++r) {
    int b0 = t * C;
    int s = 0;
    for (int j = 0; j < C; ++j) {
      int b = b0 + j;
      if (b < nBlocks) s += blockCnt[b * 4 + r];
    }
    lds[t] = s;
    __syncthreads();
    int v = s;
    for (int o = 1; o < 256; o <<= 1) {
      int u = (t >= o) ? lds[t - o] : 0;
      __syncthreads();
      v += u;
      lds[t] = v;
      __syncthreads();
    }
    int run = offs_s[r] + (v - s);
    for (int j = 0; j < C; ++j) {
      int b = b0 + j;
      if (b < nBlocks) {
        blockBase[b * 4 + r] = run;
        run += blockCnt[b * 4 + r];
      }
    }
    __syncthreads();
  }
}

__global__ void scatter_kernel(const int* __restrict__ etype, const int* __restrict__ blockBase,
                               int* __restrict__ sorted, int E) {
  __shared__ int wcnt[4][4];
  int i = blockIdx.x * 256 + threadIdx.x;
  int rt = (i < E) ? etype[i] : -1;
  int wave = threadIdx.x >> 6, lane = threadIdx.x & 63;
  unsigned long long ltmask = (lane == 0) ? 0ull : (~0ull >> (64 - lane));
  int myrank = 0;
#pragma unroll
  for (int r = 0; r < 4; ++r) {
    unsigned long long m = __ballot(rt == r);
    if (lane == 0) wcnt[wave][r] = __popcll(m);
    if (rt == r) myrank = __popcll(m & ltmask);
  }
  __syncthreads();
  if (rt >= 0) {
    int wb = 0;
#pragma unroll
    for (int w = 0; w < 3; ++w) if (w < wave) wb += wcnt[w][rt];
    sorted[blockBase[blockIdx.x * 4 + rt] + wb + myrank] = i;
  }
}

// ---------- streaming MFMA GEMM: A staged once, loop sides x col-chunks ----------
// A [M x 128] bf16; per side s: Bt_s [nch*64 x 128] bf16, out_s [M x (nch*64)].
// grid: (ceil(M/128)); block 256 = 4 waves, each wave 32 rows.
__global__ __launch_bounds__(256) void proj_multi_kernel(
    const __hip_bfloat16* __restrict__ A,
    const __hip_bfloat16* __restrict__ Bt0, const float* __restrict__ bias0,
    __hip_bfloat16* __restrict__ out0,
    const __hip_bfloat16* __restrict__ Bt1, const float* __restrict__ bias1,
    __hip_bfloat16* __restrict__ out1,
    int M, int nch, int sides, int act)
{
  __shared__ __align__(16) short As[128 * 136];
  __shared__ __align__(16) short Bs[2][64 * 136];
  int tid = threadIdx.x;
  int rowBase = blockIdx.x * 128;
  int wid = tid >> 6, lane = tid & 63;
  int m16 = lane & 15, q = lane >> 4;
  int total = nch * sides;

  // stage A tile 128x128 once
#pragma unroll
  for (int t = 0; t < 8; ++t) {
    int c = tid + t * 256;
    int row = c >> 4, kk = (c & 15) << 3;
    int grow = rowBase + row;
    short8 va;
    if (grow < M) va = *(const short8*)(const void*)(A + (size_t)grow * 128 + kk);
    else { for (int zz = 0; zz < 8; ++zz) va[zz] = 0; }
    *(short8*)(void*)(As + row * 136 + kk) = va;
  }
  __syncthreads();
  // hoist A fragments to registers (never touch As again)
  short8 af[4][2];
#pragma unroll
  for (int ks = 0; ks < 4; ++ks)
#pragma unroll
    for (int mi = 0; mi < 2; ++mi)
      af[ks][mi] = *(const short8*)(const void*)(As + (wid * 32 + mi * 16 + m16) * 136 + (ks << 5) + (q << 3));

  // stage B chunk 0 into buf 0
  {
    const __hip_bfloat16* Bt = Bt0;
#pragma unroll
    for (int t = 0; t < 4; ++t) {
      int c = tid + t * 256;
      int row = c >> 4, kk = (c & 15) << 3;
      *(short8*)(void*)(Bs[0] + row * 136 + kk) =
        *(const short8*)(const void*)(Bt + (size_t)row * 128 + kk);
    }
  }
  __syncthreads();

  int p = 0;
  for (int cb = 0; cb < total; ++cb) {
    int side = cb >= nch;
    int colBase = (side ? (cb - nch) : cb) * 64;
    // compute from buf p
    f32x4 acc[2][4];
#pragma unroll
    for (int mi = 0; mi < 2; ++mi)
#pragma unroll
      for (int ni = 0; ni < 4; ++ni) {
        acc[mi][ni][0] = 0.f; acc[mi][ni][1] = 0.f;
        acc[mi][ni][2] = 0.f; acc[mi][ni][3] = 0.f;
      }
#pragma unroll
    for (int ks = 0; ks < 4; ++ks) {
      int kof = (ks << 5) + (q << 3);
      short8 bfr[4];
#pragma unroll
      for (int ni = 0; ni < 4; ++ni)
        bfr[ni] = *(const short8*)(const void*)(Bs[p] + (ni * 16 + m16) * 136 + kof);
#pragma unroll
      for (int mi = 0; mi < 2; ++mi)
#pragma unroll
        for (int ni = 0; ni < 4; ++ni)
          acc[mi][ni] = __builtin_amdgcn_mfma_f32_16x16x32_bf16(af[ks][mi], bfr[ni], acc[mi][ni], 0, 0, 0);
    }
    // stage next chunk into buf p^1
    if (cb + 1 < total) {
      int nc = cb + 1;
      int nside = nc >= nch;
      int ncol = (nside ? (nc - nch) : nc) * 64;
      const __hip_bfloat16* Bt = nside ? Bt1 : Bt0;
#pragma unroll
      for (int t = 0; t < 4; ++t) {
        int c = tid + t * 256;
        int row = c >> 4, kk = (c & 15) << 3;
        *(short8*)(void*)(Bs[p ^ 1] + row * 136 + kk) =
          *(const short8*)(const void*)(Bt + (size_t)(ncol + row) * 128 + kk);
      }
    }
    // epilogue for chunk cb
    {
      const float* bias = side ? bias1 : bias0;
      __hip_bfloat16* out = side ? out1 : out0;
      int ldc = nch * 64;
#pragma unroll
      for (int mi = 0; mi < 2; ++mi)
#pragma unroll
        for (int ni = 0; ni < 4; ++ni) {
          int col = colBase + ni * 16 + m16;
          float bv = bias[col];
#pragma unroll
          for (int reg = 0; reg < 4; ++reg) {
            int row = rowBase + wid * 32 + mi * 16 + (q << 2) + reg;
            if (row < M) {
              float t = acc[mi][ni][reg] + bv;
              if (act) t = t / (1.f + __expf(-t));
              out[(size_t)row * ldc + col] = __float2bfloat16(t);
            }
          }
        }
    }
    __syncthreads();
    p ^= 1;
  }
}

// ---------- MFMA bf16 GEMM (generic, used for FFN2): out = A @ Bt^T + bias ----------
__global__ __launch_bounds__(256) void mfma_gemm_kernel(
    const __hip_bfloat16* __restrict__ A,
    const __hip_bfloat16* __restrict__ Bt, const float* __restrict__ bias,
    float* __restrict__ Cout, int M, int K, int Ncols)
{
  __shared__ __align__(16) short As[128 * 136];
  __shared__ __align__(16) short Bs[64 * 136];
  int tid = threadIdx.x;
  int rowBase = blockIdx.y * 128, colBase = blockIdx.x * 64;
  int wid = tid >> 6, lane = tid & 63;
  int m16 = lane & 15, q = lane >> 4;

  f32x4 acc[2][4];
#pragma unroll
  for (int mi = 0; mi < 2; ++mi)
#pragma unroll
    for (int ni = 0; ni < 4; ++ni) {
      acc[mi][ni][0] = 0.f; acc[mi][ni][1] = 0.f;
      acc[mi][ni][2] = 0.f; acc[mi][ni][3] = 0.f;
    }

#pragma unroll 1
  for (int kc = 0; kc < K; kc += 128) {
#pragma unroll
    for (int t = 0; t < 8; ++t) {
      int c = tid + t * 256;
      int row = c >> 4, kk = (c & 15) << 3;
      int grow = rowBase + row;
      short8 va;
      if (grow < M) va = *(const short8*)(const void*)(A + (size_t)grow * K + kc + kk);
      else { for (int zz = 0; zz < 8; ++zz) va[zz] = 0; }
      *(short8*)(void*)(As + row * 136 + kk) = va;
    }
#pragma unroll
    for (int t = 0; t < 4; ++t) {
      int c = tid + t * 256;
      int row = c >> 4, kk = (c & 15) << 3;
      *(short8*)(void*)(Bs + row * 136 + kk) =
        *(const short8*)(const void*)(Bt + (size_t)(colBase + row) * K + kc + kk);
    }
    __syncthreads();
#pragma unroll
    for (int ks = 0; ks < 4; ++ks) {
      int kof = (ks << 5) + (q << 3);
      short8 af[2], bfr[4];
#pragma unroll
      for (int mi = 0; mi < 2; ++mi)
        af[mi] = *(const short8*)(const void*)(As + (wid * 32 + mi * 16 + m16) * 136 + kof);
#pragma unroll
      for (int ni = 0; ni < 4; ++ni)
        bfr[ni] = *(const short8*)(const void*)(Bs + (ni * 16 + m16) * 136 + kof);
#pragma unroll
      for (int mi = 0; mi < 2; ++mi)
#pragma unroll
        for (int ni = 0; ni < 4; ++ni)
          acc[mi][ni] = __builtin_amdgcn_mfma_f32_16x16x32_bf16(af[mi], bfr[ni], acc[mi][ni], 0, 0, 0);
    }
    __syncthreads();
  }
#pragma unroll
  for (int mi = 0; mi < 2; ++mi)
#pragma unroll
    for (int ni = 0; ni < 4; ++ni) {
      int col = colBase + ni * 16 + m16;
      float bv = bias[col];
#pragma unroll
      for (int reg = 0; reg < 4; ++reg) {
        int row = rowBase + wid * 32 + mi * 16 + (q << 2) + reg;
        if (row < M) Cout[(size_t)row * Ncols + col] = acc[mi][ni][reg] + bv;
      }
    }
}

// ---------- per-edge score -> alpha + denom (relation r) ----------
__global__ __launch_bounds__(256) void score_kernel(
    const int* __restrict__ sorted, const int* __restrict__ offs, int r,
    const int* __restrict__ eidx, const float* __restrict__ eattr,
    const float* __restrict__ W_e, const float* __restrict__ att,
    const __hip_bfloat16* __restrict__ xlr, const __hip_bfloat16* __restrict__ xrr,
    float* __restrict__ alpha, float* __restrict__ denom, int N, int E)
{
  __shared__ float We_s[16 * 512];
  __shared__ float att_s[512];
  int tid = threadIdx.x;
#pragma unroll
  for (int t = 0; t < 32; ++t) {
    int idx = tid + (t << 8);
    We_s[idx] = W_e[((size_t)r * 24 + (idx >> 9)) * 512 + (idx & 511)];
  }
  att_s[tid]       = att[r * 512 + tid];
  att_s[tid + 256] = att[r * 512 + tid + 256];
  __syncthreads();

  int base = offs[r], end = offs[r + 1];
  int lane = tid & 63;
  int head = lane >> 4;
  int wave = (blockIdx.x << 2) + (tid >> 6);
  int nw = gridDim.x << 2;
  float4 atv0 = *(const float4*)(att_s + lane * 8);
  float4 atv1 = *(const float4*)(att_s + lane * 8 + 4);

  for (int i = base + wave; i < end; i += nw) {
    int eid = sorted[i];
    if (eid < 0) continue;
    int src = eidx[eid], dst = eidx[E + eid];
    float4 a0 = *(const float4*)(eattr + (size_t)eid * 16);
    float4 a1 = *(const float4*)(eattr + (size_t)eid * 16 + 4);
    float4 a2 = *(const float4*)(eattr + (size_t)eid * 16 + 8);
    float4 a3 = *(const float4*)(eattr + (size_t)eid * 16 + 12);
    float4 lv = *(const float4*)(const void*)(xlr + (size_t)src * 512 + lane * 8);
    float4 rv = *(const float4*)(const void*)(xrr + (size_t)dst * 512 + lane * 8);
    const unsigned* lw = (const unsigned*)&lv;
    const unsigned* rw = (const unsigned*)&rv;
    float x[8];
#pragma unroll
    for (int j = 0; j < 4; ++j) {
      x[2*j]   = __uint_as_float(lw[j] << 16)         + __uint_as_float(rw[j] << 16);
      x[2*j+1] = __uint_as_float(lw[j] & 0xffff0000u) + __uint_as_float(rw[j] & 0xffff0000u);
    }
    float aa[16] = {a0.x,a0.y,a0.z,a0.w, a1.x,a1.y,a1.z,a1.w,
                    a2.x,a2.y,a2.z,a2.w, a3.x,a3.y,a3.z,a3.w};
    float ef[8] = {0.f,0.f,0.f,0.f,0.f,0.f,0.f,0.f};
#pragma unroll
    for (int k = 0; k < 16; ++k) {
      float4 w0 = *(const float4*)(We_s + k * 512 + lane * 8);
      float4 w1 = *(const float4*)(We_s + k * 512 + lane * 8 + 4);
      ef[0] += aa[k]*w0.x; ef[1] += aa[k]*w0.y; ef[2] += aa[k]*w0.z; ef[3] += aa[k]*w0.w;
      ef[4] += aa[k]*w1.x; ef[5] += aa[k]*w1.y; ef[6] += aa[k]*w1.z; ef[7] += aa[k]*w1.w;
    }
    const float* at = (const float*)&atv0;
    float s = 0.f;
#pragma unroll
    for (int j = 0; j < 8; ++j) {
      float xv = x[j] + ef[j];
      xv = (xv > 0.f) ? xv : NEG * xv;
      s += xv * ((j < 4) ? at[j] : ((const float*)&atv1)[j - 4]);
    }
    s += __shfl_xor(s, 1);
    s += __shfl_xor(s, 2);
    s += __shfl_xor(s, 4);
    s += __shfl_xor(s, 8);
    if ((lane & 15) == 0) {
      float al = __expf(s);
      alpha[(size_t)eid * 4 + head] = al;
      atomicAdd(&denom[((size_t)r * N + dst) * 4 + head], al);
    }
  }
}

// ---------- aggregate (relation r) ----------
__global__ __launch_bounds__(256) void agg_kernel(
    const int* __restrict__ sorted, const int* __restrict__ offs, int r,
    const int* __restrict__ eidx, const float* __restrict__ alpha,
    const float* __restrict__ denom, const __hip_bfloat16* __restrict__ xlr,
    const float* __restrict__ gw, float* __restrict__ hmsg, int N, int E)
{
  int base = offs[r], end = offs[r + 1];
  float g = 0.25f * gw[r];
  int lane = threadIdx.x & 63;
  int wave = (blockIdx.x << 2) + (threadIdx.x >> 6);
  int nw = gridDim.x << 2;
  int col = lane * 2;
  for (int i = base + wave; i < end; i += nw) {
    int eid = sorted[i];
    if (eid < 0) continue;
    int src = eidx[eid], dst = eidx[E + eid];
    float4 al = *(const float4*)(alpha + (size_t)eid * 4);
    float4 dn = *(const float4*)(denom + ((size_t)r * N + dst) * 4);
    float coef[4] = {g * al.x / dn.x, g * al.y / dn.y, g * al.z / dn.z, g * al.w / dn.w};
    float s0 = 0.f, s1 = 0.f;
#pragma unroll
    for (int hh = 0; hh < 4; ++hh) {
      unsigned pw = *(const unsigned*)(const void*)(xlr + (size_t)src * 512 + hh * 128 + col);
      s0 += coef[hh] * __uint_as_float(pw << 16);
      s1 += coef[hh] * __uint_as_float(pw & 0xffff0000u);
    }
    atomicAdd(&hmsg[(size_t)dst * 128 + col],     s0);
    atomicAdd(&hmsg[(size_t)dst * 128 + col + 1], s1);
  }
}

// ---------- layernorm over 128 ----------
__global__ __launch_bounds__(256) void ln_kernel(
    const float* __restrict__ X, const float* __restrict__ Y,
    const float* __restrict__ g, const float* __restrict__ b,
    float* __restrict__ out, __hip_bfloat16* __restrict__ outbf, int N)
{
  int w = (int)((blockIdx.x * (unsigned)blockDim.x + threadIdx.x) >> 6);
  int lane = threadIdx.x & 63;
  if (w >= N) return;
  int c = lane * 2;
  float2 xv = *(const float2*)(X + (size_t)w * 128 + c);
  float2 yv = *(const float2*)(Y + (size_t)w * 128 + c);
  float v0 = xv.x + yv.x, v1 = xv.y + yv.y;
  float s1 = v0 + v1, s2 = v0 * v0 + v1 * v1;
#pragma unroll
  for (int off = 1; off < 64; off <<= 1) {
    s1 += __shfl_xor(s1, off);
    s2 += __shfl_xor(s2, off);
  }
  float mu = s1 * (1.f / 128.f);
  float var = s2 * (1.f / 128.f) - mu * mu;
  float rstd = rsqrtf(var + EPSLN);
  float o0 = (v0 - mu) * rstd * g[c]     + b[c];
  float o1 = (v1 - mu) * rstd * g[c + 1] + b[c + 1];
  out[(size_t)w * 128 + c]     = o0;
  out[(size_t)w * 128 + c + 1] = o1;
  if (outbf) {
    outbf[(size_t)w * 128 + c]     = __float2bfloat16(o0);
    outbf[(size_t)w * 128 + c + 1] = __float2bfloat16(o1);
  }
}

extern "C" void kernel_launch(void* const* d_in, const int* in_sizes, int n_in,
                              void* d_out, int out_size, void* d_ws, size_t ws_size,
                              hipStream_t stream) {
  const float* h       = (const float*)d_in[0];
  const int*   eidx    = (const int*)d_in[1];
  const float* eattr   = (const float*)d_in[2];
  const int*   etype   = (const int*)d_in[3];
  const float* rel_emb = (const float*)d_in[4];
  const float* W_l     = (const float*)d_in[5];
  const float* b_l     = (const float*)d_in[6];
  const float* W_r     = (const float*)d_in[7];
  const float* b_r     = (const float*)d_in[8];
  const float* W_e     = (const float*)d_in[9];
  const float* att     = (const float*)d_in[10];
  const float* bias    = (const float*)d_in[11];
  const float* gate    = (const float*)d_in[12];
  const float* g1      = (const float*)d_in[13];
  const float* bt1     = (const float*)d_in[14];
  const float* g2      = (const float*)d_in[15];
  const float* bt2     = (const float*)d_in[16];
  const float* Wf1     = (const float*)d_in[17];
  const float* bf1     = (const float*)d_in[18];
  const float* Wf2     = (const float*)d_in[19];
  const float* bf2     = (const float*)d_in[20];

  const int N = in_sizes[0] / NF;     // 40000
  const int E = in_sizes[3];          // 150000
  const int nTiles = (E + 4 * 63 + 63) / 64;
  const int sortedN = nTiles * 64;
  const int Mtiles = (N + 127) / 128;
  const int histBlocks = (E + 255) / 256;

  // workspace carve (~120 MB peak)
  char* ws = (char*)d_ws;
  size_t off = 0;
  auto carve = [&](size_t bytes) -> void* {
    void* p = ws + off;
    off = (off + bytes + 255) & ~(size_t)255;
    return p;
  };
  __hip_bfloat16* xl_r  = (__hip_bfloat16*)carve((size_t)N * 512 * 2);
  __hip_bfloat16* xr_r  = (__hip_bfloat16*)carve((size_t)N * 512 * 2);
  __hip_bfloat16* hbf   = (__hip_bfloat16*)carve((size_t)N * 128 * 2);
  __hip_bfloat16* Wlt   = (__hip_bfloat16*)carve((size_t)4 * 512 * 128 * 2);
  __hip_bfloat16* Wrt   = (__hip_bfloat16*)carve((size_t)4 * 512 * 128 * 2);
  __hip_bfloat16* Wf1t  = (__hip_bfloat16*)carve((size_t)256 * 128 * 2);
  __hip_bfloat16* Wf2t  = (__hip_bfloat16*)carve((size_t)128 * 256 * 2);
  float*    bias_c = (float*)carve((size_t)4 * 512 * 4);
  float*    alpha  = (float*)carve((size_t)E * 4 * 4);
  float*    denom  = (float*)carve((size_t)4 * N * 4 * 4);
  float*    hmsg   = (float*)carve((size_t)N * 128 * 4);
  int*      sorted = (int*)carve((size_t)sortedN * 4);
  int*      blockCnt  = (int*)carve((size_t)histBlocks * 4 * 4);
  int*      blockBase = (int*)carve((size_t)histBlocks * 4 * 4);
  int*      offsb  = (int*)carve(64);
  float*    gw     = (float*)carve(256);
  // FFN overlays onto xl_r/xr_r (dead after relation loop)
  float*          h1   = (float*)(ws + 0);
  __hip_bfloat16* h1bf = (__hip_bfloat16*)(ws + (size_t)N * 128 * 4);
  __hip_bfloat16* uffn = (__hip_bfloat16*)(ws + (size_t)N * 128 * 6);
  float*          yffn = (float*)(ws + (size_t)N * 128 * 6 + (size_t)N * 256 * 2);
  float*          out  = (float*)d_out;

  // init + prep
  init_gw_kernel<<<1, 64, 0, stream>>>(gate, gw);
  {
    int ndenom = 4 * N * 4;
    int mx = (ndenom > sortedN) ? ndenom : sortedN;
    init_all_kernel<<<(mx + 255) / 256, 256, 0, stream>>>(denom, sorted, ndenom, sortedN);
  }
  init_hmsg_kernel<<<(N * 128 + 255) / 256, 256, 0, stream>>>(gw, bias, hmsg, N * 128);
  cvt_bf16_kernel<<<(N * 128 / 4 + 255) / 256, 256, 0, stream>>>(h, hbf, N * 128);
  transpose_bf16_kernel<<<(4 * 128 * 512 + 255) / 256, 256, 0, stream>>>(W_l, Wlt, 128, 512, 4 * 128 * 512);
  transpose_bf16_kernel<<<(4 * 128 * 512 + 255) / 256, 256, 0, stream>>>(W_r, Wrt, 128, 512, 4 * 128 * 512);
  transpose_bf16_kernel<<<(128 * 256 + 255) / 256, 256, 0, stream>>>(Wf1, Wf1t, 128, 256, 128 * 256);
  transpose_bf16_kernel<<<(256 * 128 + 255) / 256, 256, 0, stream>>>(Wf2, Wf2t, 256, 128, 256 * 128);
  prep_bias_kernel<<<(4 * 512 + 255) / 256, 256, 0, stream>>>(b_r, rel_emb, W_e, bias_c);
  // atomic-free counting sort
  blockhist_kernel<<<histBlocks, 256, 0, stream>>>(etype, blockCnt, E);
  scan_kernel<<<1, 256, 0, stream>>>(blockCnt, blockBase, offsb, histBlocks);
  scatter_kernel<<<histBlocks, 256, 0, stream>>>(etype, blockBase, sorted, E);

  // per-relation: proj (xl_r, xr_r) -> score/alpha/denom -> aggregate
  for (int r = 0; r < 4; ++r) {
    proj_multi_kernel<<<Mtiles, 256, 0, stream>>>(
        hbf,
        Wlt + (size_t)r * 512 * 128, b_l + r * 512, xl_r,
        Wrt + (size_t)r * 512 * 128, bias_c + r * 512, xr_r,
        N, 8, 2, 0);
    score_kernel<<<1024, 256, 0, stream>>>(sorted, offsb, r, eidx, eattr, W_e, att,
                                           xl_r, xr_r, alpha, denom, N, E);
    agg_kernel<<<1024, 256, 0, stream>>>(sorted, offsb, r, eidx, alpha, denom,
                                         xl_r, gw, hmsg, N, E);
  }

  // h1 = LN(h + hmsg); also bf16 copy for FFN
  ln_kernel<<<(N + 3) / 4, 256, 0, stream>>>(h, hmsg, g1, bt1, h1, h1bf, N);
  // u = silu(h1 @ Wf1 + bf1)  (bf16 out, streaming kernel, 4 chunks)
  proj_multi_kernel<<<Mtiles, 256, 0, stream>>>(
      h1bf, Wf1t, bf1, uffn, Wf1t, bf1, uffn, N, 4, 1, 1);
  // y = u @ Wf2 + bf2  (fp32 out, K=256)
  mfma_gemm_kernel<<<dim3(NF / 64, Mtiles), 256, 0, stream>>>(
      uffn, Wf2t, bf2, yffn, N, 256, NF);
  // out = LN(h1 + y)
  ln_kernel<<<(N + 3) / 4, 256, 0, stream>>>(h1, yffn, g2, bt2, out, nullptr, N);
}

// Round 8
// 630.759 us; speedup vs baseline: 1.2187x; 1.2187x over previous
//
#include <hip/hip_runtime.h>
#include <hip/hip_bf16.h>

#define NF   128
#define HCC  512
#define FFND 256
#define NEG  0.2f
#define EPSLN 1e-5f

typedef __attribute__((ext_vector_type(8))) short short8;
typedef __attribute__((ext_vector_type(4))) float f32x4;

// ---------- tiny init / prep ----------
__global__ void init_gw_kernel(const float* __restrict__ gate, float* __restrict__ gw) {
  if (threadIdx.x == 0 && blockIdx.x == 0) {
    float a = gate[0], b = gate[1], c = gate[2], d = gate[3];
    float m = fmaxf(fmaxf(a, b), fmaxf(c, d));
    float e0 = __expf(a - m), e1 = __expf(b - m), e2 = __expf(c - m), e3 = __expf(d - m);
    float s = e0 + e1 + e2 + e3;
    gw[0] = e0 / s; gw[1] = e1 / s; gw[2] = e2 / s; gw[3] = e3 / s;
  }
}

__global__ void init_all_kernel(float* __restrict__ denom, int* __restrict__ sorted,
                                int ndenom, int nsorted) {
  int i = blockIdx.x * 256 + threadIdx.x;
  if (i < ndenom)  denom[i] = 0.f;
  if (i < nsorted) sorted[i] = -1;
}

__global__ void init_hmsg_kernel(const float* __restrict__ gw, const float* __restrict__ bias,
                                 float* __restrict__ hmsg, int total) {
  int i = blockIdx.x * 256 + threadIdx.x;
  if (i < total) {
    int c = i & 127;
    hmsg[i] = gw[0]*bias[c] + gw[1]*bias[128+c] + gw[2]*bias[256+c] + gw[3]*bias[384+c];
  }
}

// fp32 [batch][rows][cols] -> bf16 [batch][cols][rows]
__global__ void transpose_bf16_kernel(const float* __restrict__ in, __hip_bfloat16* __restrict__ out,
                                      int rows, int cols, int total) {
  int i = blockIdx.x * 256 + threadIdx.x;
  if (i >= total) return;
  int per = rows * cols;
  int b = i / per, rem = i % per;
  int rr = rem / cols, cc = rem % cols;
  out[(size_t)b * per + (size_t)cc * rows + rr] = __float2bfloat16(in[i]);
}

__global__ void cvt_bf16_kernel(const float* __restrict__ in, __hip_bfloat16* __restrict__ out, int n) {
  int i4 = (blockIdx.x * 256 + threadIdx.x) * 4;
  if (i4 >= n) return;
  float4 v = *(const float4*)(in + i4);
  out[i4]     = __float2bfloat16(v.x);
  out[i4 + 1] = __float2bfloat16(v.y);
  out[i4 + 2] = __float2bfloat16(v.z);
  out[i4 + 3] = __float2bfloat16(v.w);
}

// bias_comb[r][512] = b_r[r] + rel_emb[r] @ W_e[r][16:24]
__global__ void prep_bias_kernel(const float* __restrict__ b_r, const float* __restrict__ rel_emb,
                                 const float* __restrict__ W_e, float* __restrict__ bias_comb) {
  int i = blockIdx.x * 256 + threadIdx.x;
  if (i >= 4 * 512) return;
  int col = i & 511, r = i >> 9;
  float v = b_r[i];
#pragma unroll
  for (int j = 0; j < 8; ++j)
    v += rel_emb[r * 8 + j] * W_e[(size_t)r * 24 * 512 + (size_t)(16 + j) * 512 + col];
  bias_comb[i] = v;
}

// ---------- atomic-free counting sort by relation ----------
__global__ void blockhist_kernel(const int* __restrict__ etype, int* __restrict__ blockCnt, int E) {
  __shared__ int wcnt[4][4];
  int i = blockIdx.x * 256 + threadIdx.x;
  int rt = (i < E) ? etype[i] : -1;
  int wave = threadIdx.x >> 6, lane = threadIdx.x & 63;
#pragma unroll
  for (int r = 0; r < 4; ++r) {
    unsigned long long m = __ballot(rt == r);
    if (lane == 0) wcnt[wave][r] = __popcll(m);
  }
  __syncthreads();
  if (threadIdx.x < 4) {
    int r = threadIdx.x;
    blockCnt[blockIdx.x * 4 + r] = wcnt[0][r] + wcnt[1][r] + wcnt[2][r] + wcnt[3][r];
  }
}

__global__ void scan_kernel(const int* __restrict__ blockCnt, int* __restrict__ blockBase,
                            int* __restrict__ offs, int nBlocks) {
  __shared__ int lds[256];
  __shared__ int offs_s[5];
  __shared__ int tot_s[4];
  int t = threadIdx.x;
  int C = (nBlocks + 255) / 256;
  for (int r = 0; r < 4; ++r) {
    int s = 0;
    for (int b = t; b < nBlocks; b += 256) s += blockCnt[b * 4 + r];
    lds[t] = s;
    __syncthreads();
    for (int o = 128; o > 0; o >>= 1) {
      if (t < o) lds[t] += lds[t + o];
      __syncthreads();
    }
    if (t == 0) tot_s[r] = lds[0];
    __syncthreads();
  }
  if (t == 0) {
    int o = 0;
    offs_s[0] = 0;
    for (int r = 0; r < 4; ++r) { o += ((tot_s[r] + 63) >> 6) << 6; offs_s[r + 1] = o; }
    for (int r = 0; r < 5; ++r) offs[r] = offs_s[r];
  }
  __syncthreads();
  for (int r = 0; r < 4; ++r) {
    int b0 = t * C;
    int s = 0;
    for (int j = 0; j < C; ++j) {
      int b = b0 + j;
      if (b < nBlocks) s += blockCnt[b * 4 + r];
    }
    lds[t] = s;
    __syncthreads();
    int v = s;
    for (int o = 1; o < 256; o <<= 1) {
      int u = (t >= o) ? lds[t - o] : 0;
      __syncthreads();
      v += u;
      lds[t] = v;
      __syncthreads();
    }
    int run = offs_s[r] + (v - s);
    for (int j = 0; j < C; ++j) {
      int b = b0 + j;
      if (b < nBlocks) {
        blockBase[b * 4 + r] = run;
        run += blockCnt[b * 4 + r];
      }
    }
    __syncthreads();
  }
}

__global__ void scatter_kernel(const int* __restrict__ etype, const int* __restrict__ blockBase,
                               int* __restrict__ sorted, int E) {
  __shared__ int wcnt[4][4];
  int i = blockIdx.x * 256 + threadIdx.x;
  int rt = (i < E) ? etype[i] : -1;
  int wave = threadIdx.x >> 6, lane = threadIdx.x & 63;
  unsigned long long ltmask = (lane == 0) ? 0ull : (~0ull >> (64 - lane));
  int myrank = 0;
#pragma unroll
  for (int r = 0; r < 4; ++r) {
    unsigned long long m = __ballot(rt == r);
    if (lane == 0) wcnt[wave][r] = __popcll(m);
    if (rt == r) myrank = __popcll(m & ltmask);
  }
  __syncthreads();
  if (rt >= 0) {
    int wb = 0;
#pragma unroll
    for (int w = 0; w < 3; ++w) if (w < wave) wb += wcnt[w][rt];
    sorted[blockBase[blockIdx.x * 4 + rt] + wb + myrank] = i;
  }
}

// ---------- streaming MFMA GEMM, swapped operands: coalesced 8B bf16 stores ----------
// A [M x 128] bf16; Bt [nch*64 x 128] bf16; out [M x nch*64] bf16.
// grid: (ceil(M/128), sides). A fragments direct from global (no As LDS).
// Each lane: fixed node row, acc regs = 4 consecutive output cols.
__global__ __launch_bounds__(256) void proj_multi_kernel(
    const __hip_bfloat16* __restrict__ A,
    const __hip_bfloat16* __restrict__ Bt0, const float* __restrict__ bias0,
    __hip_bfloat16* __restrict__ out0,
    const __hip_bfloat16* __restrict__ Bt1, const float* __restrict__ bias1,
    __hip_bfloat16* __restrict__ out1,
    int M, int nch, int act)
{
  __shared__ __align__(16) short Bs[2][64 * 136];
  int side = blockIdx.y;
  const __hip_bfloat16* Bt = side ? Bt1 : Bt0;
  const float* bias = side ? bias1 : bias0;
  __hip_bfloat16* outp = side ? out1 : out0;
  int ldc = nch * 64;
  int tid = threadIdx.x;
  int rowBase = blockIdx.x * 128;
  int wid = tid >> 6, lane = tid & 63;
  int m16 = lane & 15, q = lane >> 4;

  // A fragments direct from global: af[ks][mi] covers k = ks*32 + q*8 .. +7
  short8 af[4][2];
#pragma unroll
  for (int mi = 0; mi < 2; ++mi) {
    int row = rowBase + wid * 32 + mi * 16 + m16;
    const __hip_bfloat16* ap = A + (size_t)row * 128 + q * 8;
    bool ok = row < M;
#pragma unroll
    for (int ks = 0; ks < 4; ++ks) {
      if (ok) af[ks][mi] = *(const short8*)(const void*)(ap + ks * 32);
      else { short8 z; for (int t = 0; t < 8; ++t) z[t] = 0; af[ks][mi] = z; }
    }
  }

  // stage B chunk 0
#pragma unroll
  for (int t = 0; t < 4; ++t) {
    int c = tid + t * 256;
    int row = c >> 4, kk = (c & 15) << 3;
    *(short8*)(void*)(Bs[0] + row * 136 + kk) =
      *(const short8*)(const void*)(Bt + (size_t)row * 128 + kk);
  }
  __syncthreads();

  int p = 0;
  for (int cb = 0; cb < nch; ++cb) {
    int colBase = cb * 64;
    f32x4 acc[2][4];
#pragma unroll
    for (int mi = 0; mi < 2; ++mi)
#pragma unroll
      for (int ni = 0; ni < 4; ++ni) {
        acc[mi][ni][0] = 0.f; acc[mi][ni][1] = 0.f;
        acc[mi][ni][2] = 0.f; acc[mi][ni][3] = 0.f;
      }
#pragma unroll
    for (int ks = 0; ks < 4; ++ks) {
      int kof = (ks << 5) + (q << 3);
      short8 bfr[4];
#pragma unroll
      for (int ni = 0; ni < 4; ++ni)
        bfr[ni] = *(const short8*)(const void*)(Bs[p] + (ni * 16 + m16) * 136 + kof);
#pragma unroll
      for (int mi = 0; mi < 2; ++mi)
#pragma unroll
        for (int ni = 0; ni < 4; ++ni)
          acc[mi][ni] = __builtin_amdgcn_mfma_f32_16x16x32_bf16(bfr[ni], af[ks][mi], acc[mi][ni], 0, 0, 0);
    }
    // prefetch next B chunk
    if (cb + 1 < nch) {
#pragma unroll
      for (int t = 0; t < 4; ++t) {
        int c = tid + t * 256;
        int row = c >> 4, kk = (c & 15) << 3;
        *(short8*)(void*)(Bs[p ^ 1] + row * 136 + kk) =
          *(const short8*)(const void*)(Bt + (size_t)(colBase + 64 + row) * 128 + kk);
      }
    }
    // epilogue: node = rowBase + wid*32 + mi*16 + m16 ; cols = colBase + ni*16 + q*4 + reg
#pragma unroll
    for (int mi = 0; mi < 2; ++mi) {
      int row = rowBase + wid * 32 + mi * 16 + m16;
      if (row < M) {
#pragma unroll
        for (int ni = 0; ni < 4; ++ni) {
          int col0 = colBase + ni * 16 + q * 4;
          float4 b4 = *(const float4*)(bias + col0);
          float v0 = acc[mi][ni][0] + b4.x;
          float v1 = acc[mi][ni][1] + b4.y;
          float v2 = acc[mi][ni][2] + b4.z;
          float v3 = acc[mi][ni][3] + b4.w;
          if (act) {
            v0 = v0 / (1.f + __expf(-v0));
            v1 = v1 / (1.f + __expf(-v1));
            v2 = v2 / (1.f + __expf(-v2));
            v3 = v3 / (1.f + __expf(-v3));
          }
          __align__(8) __hip_bfloat16 tmp[4];
          tmp[0] = __float2bfloat16(v0);
          tmp[1] = __float2bfloat16(v1);
          tmp[2] = __float2bfloat16(v2);
          tmp[3] = __float2bfloat16(v3);
          *(uint2*)(void*)(outp + (size_t)row * ldc + col0) = *(const uint2*)(const void*)tmp;
        }
      }
    }
    __syncthreads();
    p ^= 1;
  }
}

// ---------- MFMA bf16 GEMM (FFN2): fp32 out, float4 stores, swapped operands ----------
__global__ __launch_bounds__(256) void mfma_gemm_kernel(
    const __hip_bfloat16* __restrict__ A,
    const __hip_bfloat16* __restrict__ Bt, const float* __restrict__ bias,
    float* __restrict__ Cout, int M, int K, int Ncols)
{
  __shared__ __align__(16) short Bs[64 * 136];
  int tid = threadIdx.x;
  int rowBase = blockIdx.y * 128, colBase = blockIdx.x * 64;
  int wid = tid >> 6, lane = tid & 63;
  int m16 = lane & 15, q = lane >> 4;

  f32x4 acc[2][4];
#pragma unroll
  for (int mi = 0; mi < 2; ++mi)
#pragma unroll
    for (int ni = 0; ni < 4; ++ni) {
      acc[mi][ni][0] = 0.f; acc[mi][ni][1] = 0.f;
      acc[mi][ni][2] = 0.f; acc[mi][ni][3] = 0.f;
    }

#pragma unroll 1
  for (int kc = 0; kc < K; kc += 128) {
#pragma unroll
    for (int t = 0; t < 4; ++t) {
      int c = tid + t * 256;
      int row = c >> 4, kk = (c & 15) << 3;
      *(short8*)(void*)(Bs + row * 136 + kk) =
        *(const short8*)(const void*)(Bt + (size_t)(colBase + row) * K + kc + kk);
    }
    __syncthreads();
    short8 af[4][2];
#pragma unroll
    for (int mi = 0; mi < 2; ++mi) {
      int row = rowBase + wid * 32 + mi * 16 + m16;
      const __hip_bfloat16* ap = A + (size_t)row * K + kc + q * 8;
      bool ok = row < M;
#pragma unroll
      for (int ks = 0; ks < 4; ++ks) {
        if (ok) af[ks][mi] = *(const short8*)(const void*)(ap + ks * 32);
        else { short8 z; for (int t2 = 0; t2 < 8; ++t2) z[t2] = 0; af[ks][mi] = z; }
      }
    }
#pragma unroll
    for (int ks = 0; ks < 4; ++ks) {
      int kof = (ks << 5) + (q << 3);
      short8 bfr[4];
#pragma unroll
      for (int ni = 0; ni < 4; ++ni)
        bfr[ni] = *(const short8*)(const void*)(Bs + (ni * 16 + m16) * 136 + kof);
#pragma unroll
      for (int mi = 0; mi < 2; ++mi)
#pragma unroll
        for (int ni = 0; ni < 4; ++ni)
          acc[mi][ni] = __builtin_amdgcn_mfma_f32_16x16x32_bf16(bfr[ni], af[ks][mi], acc[mi][ni], 0, 0, 0);
    }
    __syncthreads();
  }
#pragma unroll
  for (int mi = 0; mi < 2; ++mi) {
    int row = rowBase + wid * 32 + mi * 16 + m16;
    if (row < M) {
#pragma unroll
      for (int ni = 0; ni < 4; ++ni) {
        int col0 = colBase + ni * 16 + q * 4;
        float4 b4 = *(const float4*)(bias + col0);
        float4 v;
        v.x = acc[mi][ni][0] + b4.x;
        v.y = acc[mi][ni][1] + b4.y;
        v.z = acc[mi][ni][2] + b4.z;
        v.w = acc[mi][ni][3] + b4.w;
        *(float4*)(Cout + (size_t)row * Ncols + col0) = v;
      }
    }
  }
}

// ---------- per-edge score -> alpha + denom (relation r) ----------
__global__ __launch_bounds__(256) void score_kernel(
    const int* __restrict__ sorted, const int* __restrict__ offs, int r,
    const int* __restrict__ eidx, const float* __restrict__ eattr,
    const float* __restrict__ W_e, const float* __restrict__ att,
    const __hip_bfloat16* __restrict__ xlr, const __hip_bfloat16* __restrict__ xrr,
    float* __restrict__ alpha, float* __restrict__ denom, int N, int E)
{
  __shared__ float We_s[16 * 512];
  __shared__ float att_s[512];
  int tid = threadIdx.x;
#pragma unroll
  for (int t = 0; t < 32; ++t) {
    int idx = tid + (t << 8);
    We_s[idx] = W_e[((size_t)r * 24 + (idx >> 9)) * 512 + (idx & 511)];
  }
  att_s[tid]       = att[r * 512 + tid];
  att_s[tid + 256] = att[r * 512 + tid + 256];
  __syncthreads();

  int base = offs[r], end = offs[r + 1];
  int lane = tid & 63;
  int head = lane >> 4;
  int wave = (blockIdx.x << 2) + (tid >> 6);
  int nw = gridDim.x << 2;
  float4 atv0 = *(const float4*)(att_s + lane * 8);
  float4 atv1 = *(const float4*)(att_s + lane * 8 + 4);

  for (int i = base + wave; i < end; i += nw) {
    int eid = sorted[i];
    if (eid < 0) continue;
    int src = eidx[eid], dst = eidx[E + eid];
    float4 a0 = *(const float4*)(eattr + (size_t)eid * 16);
    float4 a1 = *(const float4*)(eattr + (size_t)eid * 16 + 4);
    float4 a2 = *(const float4*)(eattr + (size_t)eid * 16 + 8);
    float4 a3 = *(const float4*)(eattr + (size_t)eid * 16 + 12);
    float4 lv = *(const float4*)(const void*)(xlr + (size_t)src * 512 + lane * 8);
    float4 rv = *(const float4*)(const void*)(xrr + (size_t)dst * 512 + lane * 8);
    const unsigned* lw = (const unsigned*)&lv;
    const unsigned* rw = (const unsigned*)&rv;
    float x[8];
#pragma unroll
    for (int j = 0; j < 4; ++j) {
      x[2*j]   = __uint_as_float(lw[j] << 16)         + __uint_as_float(rw[j] << 16);
      x[2*j+1] = __uint_as_float(lw[j] & 0xffff0000u) + __uint_as_float(rw[j] & 0xffff0000u);
    }
    float aa[16] = {a0.x,a0.y,a0.z,a0.w, a1.x,a1.y,a1.z,a1.w,
                    a2.x,a2.y,a2.z,a2.w, a3.x,a3.y,a3.z,a3.w};
    float ef[8] = {0.f,0.f,0.f,0.f,0.f,0.f,0.f,0.f};
#pragma unroll
    for (int k = 0; k < 16; ++k) {
      float4 w0 = *(const float4*)(We_s + k * 512 + lane * 8);
      float4 w1 = *(const float4*)(We_s + k * 512 + lane * 8 + 4);
      ef[0] += aa[k]*w0.x; ef[1] += aa[k]*w0.y; ef[2] += aa[k]*w0.z; ef[3] += aa[k]*w0.w;
      ef[4] += aa[k]*w1.x; ef[5] += aa[k]*w1.y; ef[6] += aa[k]*w1.z; ef[7] += aa[k]*w1.w;
    }
    const float* at = (const float*)&atv0;
    float s = 0.f;
#pragma unroll
    for (int j = 0; j < 8; ++j) {
      float xv = x[j] + ef[j];
      xv = (xv > 0.f) ? xv : NEG * xv;
      s += xv * ((j < 4) ? at[j] : ((const float*)&atv1)[j - 4]);
    }
    s += __shfl_xor(s, 1);
    s += __shfl_xor(s, 2);
    s += __shfl_xor(s, 4);
    s += __shfl_xor(s, 8);
    if ((lane & 15) == 0) {
      float al = __expf(s);
      alpha[(size_t)eid * 4 + head] = al;
      atomicAdd(&denom[((size_t)r * N + dst) * 4 + head], al);
    }
  }
}

// ---------- aggregate (relation r) ----------
__global__ __launch_bounds__(256) void agg_kernel(
    const int* __restrict__ sorted, const int* __restrict__ offs, int r,
    const int* __restrict__ eidx, const float* __restrict__ alpha,
    const float* __restrict__ denom, const __hip_bfloat16* __restrict__ xlr,
    const float* __restrict__ gw, float* __restrict__ hmsg, int N, int E)
{
  int base = offs[r], end = offs[r + 1];
  float g = 0.25f * gw[r];
  int lane = threadIdx.x & 63;
  int wave = (blockIdx.x << 2) + (threadIdx.x >> 6);
  int nw = gridDim.x << 2;
  int col = lane * 2;
  for (int i = base + wave; i < end; i += nw) {
    int eid = sorted[i];
    if (eid < 0) continue;
    int src = eidx[eid], dst = eidx[E + eid];
    float4 al = *(const float4*)(alpha + (size_t)eid * 4);
    float4 dn = *(const float4*)(denom + ((size_t)r * N + dst) * 4);
    float coef[4] = {g * al.x / dn.x, g * al.y / dn.y, g * al.z / dn.z, g * al.w / dn.w};
    float s0 = 0.f, s1 = 0.f;
#pragma unroll
    for (int hh = 0; hh < 4; ++hh) {
      unsigned pw = *(const unsigned*)(const void*)(xlr + (size_t)src * 512 + hh * 128 + col);
      s0 += coef[hh] * __uint_as_float(pw << 16);
      s1 += coef[hh] * __uint_as_float(pw & 0xffff0000u);
    }
    atomicAdd(&hmsg[(size_t)dst * 128 + col],     s0);
    atomicAdd(&hmsg[(size_t)dst * 128 + col + 1], s1);
  }
}

// ---------- layernorm over 128 ----------
__global__ __launch_bounds__(256) void ln_kernel(
    const float* __restrict__ X, const float* __restrict__ Y,
    const float* __restrict__ g, const float* __restrict__ b,
    float* __restrict__ out, __hip_bfloat16* __restrict__ outbf, int N)
{
  int w = (int)((blockIdx.x * (unsigned)blockDim.x + threadIdx.x) >> 6);
  int lane = threadIdx.x & 63;
  if (w >= N) return;
  int c = lane * 2;
  float2 xv = *(const float2*)(X + (size_t)w * 128 + c);
  float2 yv = *(const float2*)(Y + (size_t)w * 128 + c);
  float v0 = xv.x + yv.x, v1 = xv.y + yv.y;
  float s1 = v0 + v1, s2 = v0 * v0 + v1 * v1;
#pragma unroll
  for (int off = 1; off < 64; off <<= 1) {
    s1 += __shfl_xor(s1, off);
    s2 += __shfl_xor(s2, off);
  }
  float mu = s1 * (1.f / 128.f);
  float var = s2 * (1.f / 128.f) - mu * mu;
  float rstd = rsqrtf(var + EPSLN);
  float o0 = (v0 - mu) * rstd * g[c]     + b[c];
  float o1 = (v1 - mu) * rstd * g[c + 1] + b[c + 1];
  out[(size_t)w * 128 + c]     = o0;
  out[(size_t)w * 128 + c + 1] = o1;
  if (outbf) {
    outbf[(size_t)w * 128 + c]     = __float2bfloat16(o0);
    outbf[(size_t)w * 128 + c + 1] = __float2bfloat16(o1);
  }
}

extern "C" void kernel_launch(void* const* d_in, const int* in_sizes, int n_in,
                              void* d_out, int out_size, void* d_ws, size_t ws_size,
                              hipStream_t stream) {
  const float* h       = (const float*)d_in[0];
  const int*   eidx    = (const int*)d_in[1];
  const float* eattr   = (const float*)d_in[2];
  const int*   etype   = (const int*)d_in[3];
  const float* rel_emb = (const float*)d_in[4];
  const float* W_l     = (const float*)d_in[5];
  const float* b_l     = (const float*)d_in[6];
  const float* W_r     = (const float*)d_in[7];
  const float* b_r     = (const float*)d_in[8];
  const float* W_e     = (const float*)d_in[9];
  const float* att     = (const float*)d_in[10];
  const float* bias    = (const float*)d_in[11];
  const float* gate    = (const float*)d_in[12];
  const float* g1      = (const float*)d_in[13];
  const float* bt1     = (const float*)d_in[14];
  const float* g2      = (const float*)d_in[15];
  const float* bt2     = (const float*)d_in[16];
  const float* Wf1     = (const float*)d_in[17];
  const float* bf1     = (const float*)d_in[18];
  const float* Wf2     = (const float*)d_in[19];
  const float* bf2     = (const float*)d_in[20];

  const int N = in_sizes[0] / NF;     // 40000
  const int E = in_sizes[3];          // 150000
  const int nTiles = (E + 4 * 63 + 63) / 64;
  const int sortedN = nTiles * 64;
  const int Mtiles = (N + 127) / 128;
  const int histBlocks = (E + 255) / 256;

  // workspace carve (~120 MB peak)
  char* ws = (char*)d_ws;
  size_t off = 0;
  auto carve = [&](size_t bytes) -> void* {
    void* p = ws + off;
    off = (off + bytes + 255) & ~(size_t)255;
    return p;
  };
  __hip_bfloat16* xl_r  = (__hip_bfloat16*)carve((size_t)N * 512 * 2);
  __hip_bfloat16* xr_r  = (__hip_bfloat16*)carve((size_t)N * 512 * 2);
  __hip_bfloat16* hbf   = (__hip_bfloat16*)carve((size_t)N * 128 * 2);
  __hip_bfloat16* Wlt   = (__hip_bfloat16*)carve((size_t)4 * 512 * 128 * 2);
  __hip_bfloat16* Wrt   = (__hip_bfloat16*)carve((size_t)4 * 512 * 128 * 2);
  __hip_bfloat16* Wf1t  = (__hip_bfloat16*)carve((size_t)256 * 128 * 2);
  __hip_bfloat16* Wf2t  = (__hip_bfloat16*)carve((size_t)128 * 256 * 2);
  float*    bias_c = (float*)carve((size_t)4 * 512 * 4);
  float*    alpha  = (float*)carve((size_t)E * 4 * 4);
  float*    denom  = (float*)carve((size_t)4 * N * 4 * 4);
  float*    hmsg   = (float*)carve((size_t)N * 128 * 4);
  int*      sorted = (int*)carve((size_t)sortedN * 4);
  int*      blockCnt  = (int*)carve((size_t)histBlocks * 4 * 4);
  int*      blockBase = (int*)carve((size_t)histBlocks * 4 * 4);
  int*      offsb  = (int*)carve(64);
  float*    gw     = (float*)carve(256);
  // FFN overlays onto xl_r/xr_r (dead after relation loop)
  float*          h1   = (float*)(ws + 0);
  __hip_bfloat16* h1bf = (__hip_bfloat16*)(ws + (size_t)N * 128 * 4);
  __hip_bfloat16* uffn = (__hip_bfloat16*)(ws + (size_t)N * 128 * 6);
  float*          yffn = (float*)(ws + (size_t)N * 128 * 6 + (size_t)N * 256 * 2);
  float*          out  = (float*)d_out;

  // init + prep
  init_gw_kernel<<<1, 64, 0, stream>>>(gate, gw);
  {
    int ndenom = 4 * N * 4;
    int mx = (ndenom > sortedN) ? ndenom : sortedN;
    init_all_kernel<<<(mx + 255) / 256, 256, 0, stream>>>(denom, sorted, ndenom, sortedN);
  }
  init_hmsg_kernel<<<(N * 128 + 255) / 256, 256, 0, stream>>>(gw, bias, hmsg, N * 128);
  cvt_bf16_kernel<<<(N * 128 / 4 + 255) / 256, 256, 0, stream>>>(h, hbf, N * 128);
  transpose_bf16_kernel<<<(4 * 128 * 512 + 255) / 256, 256, 0, stream>>>(W_l, Wlt, 128, 512, 4 * 128 * 512);
  transpose_bf16_kernel<<<(4 * 128 * 512 + 255) / 256, 256, 0, stream>>>(W_r, Wrt, 128, 512, 4 * 128 * 512);
  transpose_bf16_kernel<<<(128 * 256 + 255) / 256, 256, 0, stream>>>(Wf1, Wf1t, 128, 256, 128 * 256);
  transpose_bf16_kernel<<<(256 * 128 + 255) / 256, 256, 0, stream>>>(Wf2, Wf2t, 256, 128, 256 * 128);
  prep_bias_kernel<<<(4 * 512 + 255) / 256, 256, 0, stream>>>(b_r, rel_emb, W_e, bias_c);
  // atomic-free counting sort
  blockhist_kernel<<<histBlocks, 256, 0, stream>>>(etype, blockCnt, E);
  scan_kernel<<<1, 256, 0, stream>>>(blockCnt, blockBase, offsb, histBlocks);
  scatter_kernel<<<histBlocks, 256, 0, stream>>>(etype, blockBase, sorted, E);

  // per-relation: proj (xl_r, xr_r) -> score/alpha/denom -> aggregate
  for (int r = 0; r < 4; ++r) {
    proj_multi_kernel<<<dim3(Mtiles, 2), 256, 0, stream>>>(
        hbf,
        Wlt + (size_t)r * 512 * 128, b_l + r * 512, xl_r,
        Wrt + (size_t)r * 512 * 128, bias_c + r * 512, xr_r,
        N, 8, 0);
    score_kernel<<<1024, 256, 0, stream>>>(sorted, offsb, r, eidx, eattr, W_e, att,
                                           xl_r, xr_r, alpha, denom, N, E);
    agg_kernel<<<1024, 256, 0, stream>>>(sorted, offsb, r, eidx, alpha, denom,
                                         xl_r, gw, hmsg, N, E);
  }

  // h1 = LN(h + hmsg); also bf16 copy for FFN
  ln_kernel<<<(N + 3) / 4, 256, 0, stream>>>(h, hmsg, g1, bt1, h1, h1bf, N);
  // u = silu(h1 @ Wf1 + bf1)  (bf16 out, streaming kernel, 4 chunks)
  proj_multi_kernel<<<dim3(Mtiles, 1), 256, 0, stream>>>(
      h1bf, Wf1t, bf1, uffn, Wf1t, bf1, uffn, N, 4, 1);
  // y = u @ Wf2 + bf2  (fp32 out, K=256)
  mfma_gemm_kernel<<<dim3(NF / 64, Mtiles), 256, 0, stream>>>(
      uffn, Wf2t, bf2, yffn, N, 256, NF);
  // out = LN(h1 + y)
  ln_kernel<<<(N + 3) / 4, 256, 0, stream>>>(h1, yffn, g2, bt2, out, nullptr, N);
}

// Round 9
// 613.489 us; speedup vs baseline: 1.2530x; 1.0282x over previous
//
#include <hip/hip_runtime.h>
#include <hip/hip_bf16.h>

#define NF   128
#define HCC  512
#define FFND 256
#define NEG  0.2f
#define EPSLN 1e-5f

typedef __attribute__((ext_vector_type(8))) short short8;
typedef __attribute__((ext_vector_type(4))) float f32x4;

// ---------- fused prep: gw, hbf, weight transposes, bias_c, denom, sorted, hmsg ----------
__global__ void prep_all_kernel(
    const float* __restrict__ h, __hip_bfloat16* __restrict__ hbf,
    const float* __restrict__ W_l, __hip_bfloat16* __restrict__ Wlt,
    const float* __restrict__ W_r, __hip_bfloat16* __restrict__ Wrt,
    const float* __restrict__ Wf1, __hip_bfloat16* __restrict__ Wf1t,
    const float* __restrict__ Wf2, __hip_bfloat16* __restrict__ Wf2t,
    const float* __restrict__ b_r, const float* __restrict__ rel_emb,
    const float* __restrict__ W_e, float* __restrict__ bias_c,
    const float* __restrict__ gate, float* __restrict__ gw,
    const float* __restrict__ bias, float* __restrict__ hmsg,
    float* __restrict__ denom, int* __restrict__ sorted,
    int N, int sortedN)
{
  int tid0 = blockIdx.x * 256 + threadIdx.x;
  int stride = gridDim.x * 256;
  // gate softmax, locally in every thread
  float a0 = gate[0], a1 = gate[1], a2 = gate[2], a3 = gate[3];
  float mx = fmaxf(fmaxf(a0, a1), fmaxf(a2, a3));
  float e0 = __expf(a0 - mx), e1 = __expf(a1 - mx), e2 = __expf(a2 - mx), e3 = __expf(a3 - mx);
  float inv = 1.f / (e0 + e1 + e2 + e3);
  float g0 = e0 * inv, g1 = e1 * inv, g2 = e2 * inv, g3 = e3 * inv;
  if (tid0 == 0) { gw[0] = g0; gw[1] = g1; gw[2] = g2; gw[3] = g3; }
  // h -> bf16 (float4 granularity)
  for (int i = tid0; i < N * 32; i += stride) {
    float4 v = ((const float4*)h)[i];
    __align__(8) __hip_bfloat16 t[4] = {
      __float2bfloat16(v.x), __float2bfloat16(v.y),
      __float2bfloat16(v.z), __float2bfloat16(v.w)};
    ((uint2*)hbf)[i] = *(const uint2*)(const void*)t;
  }
  // W_l / W_r transpose [4][128][512] -> [4][512][128] bf16
  for (int i = tid0; i < 4 * 128 * 512; i += stride) {
    int col = i & 511, row = (i >> 9) & 127, b = i >> 16;
    size_t o = ((size_t)b << 16) + ((size_t)col << 7) + row;
    Wlt[o] = __float2bfloat16(W_l[i]);
    Wrt[o] = __float2bfloat16(W_r[i]);
  }
  // Wf1 [128][256] -> [256][128]
  for (int i = tid0; i < 128 * 256; i += stride) {
    int col = i & 255, row = i >> 8;
    Wf1t[col * 128 + row] = __float2bfloat16(Wf1[i]);
  }
  // Wf2 [256][128] -> [128][256]
  for (int i = tid0; i < 256 * 128; i += stride) {
    int col = i & 127, row = i >> 7;
    Wf2t[col * 256 + row] = __float2bfloat16(Wf2[i]);
  }
  // bias_c[r][512] = b_r + rel_emb @ W_e[16:24]
  for (int i = tid0; i < 4 * 512; i += stride) {
    int col = i & 511, r = i >> 9;
    float v = b_r[i];
#pragma unroll
    for (int j = 0; j < 8; ++j)
      v += rel_emb[r * 8 + j] * W_e[((size_t)r * 24 + 16 + j) * 512 + col];
    bias_c[i] = v;
  }
  // denom zero
  for (int i = tid0; i < N * 4; i += stride)
    ((float4*)denom)[i] = make_float4(0.f, 0.f, 0.f, 0.f);
  // sorted fill -1
  for (int i = tid0; i < sortedN; i += stride) sorted[i] = -1;
  // hmsg init = sum_r gw[r]*bias[r][c]
  for (int i = tid0; i < N * 32; i += stride) {
    int c = (i & 31) * 4;
    float4 b0 = *(const float4*)(bias + c);
    float4 b1 = *(const float4*)(bias + 128 + c);
    float4 b2 = *(const float4*)(bias + 256 + c);
    float4 b3 = *(const float4*)(bias + 384 + c);
    float4 o;
    o.x = g0 * b0.x + g1 * b1.x + g2 * b2.x + g3 * b3.x;
    o.y = g0 * b0.y + g1 * b1.y + g2 * b2.y + g3 * b3.y;
    o.z = g0 * b0.z + g1 * b1.z + g2 * b2.z + g3 * b3.z;
    o.w = g0 * b0.w + g1 * b1.w + g2 * b2.w + g3 * b3.w;
    ((float4*)hmsg)[i] = o;
  }
}

// ---------- atomic-free counting sort by relation ----------
__global__ void blockhist_kernel(const int* __restrict__ etype, int* __restrict__ blockCnt, int E) {
  __shared__ int wcnt[4][4];
  int i = blockIdx.x * 256 + threadIdx.x;
  int rt = (i < E) ? etype[i] : -1;
  int wave = threadIdx.x >> 6, lane = threadIdx.x & 63;
#pragma unroll
  for (int r = 0; r < 4; ++r) {
    unsigned long long m = __ballot(rt == r);
    if (lane == 0) wcnt[wave][r] = __popcll(m);
  }
  __syncthreads();
  if (threadIdx.x < 4) {
    int r = threadIdx.x;
    blockCnt[blockIdx.x * 4 + r] = wcnt[0][r] + wcnt[1][r] + wcnt[2][r] + wcnt[3][r];
  }
}

__global__ void scan_kernel(const int* __restrict__ blockCnt, int* __restrict__ blockBase,
                            int* __restrict__ offs, int nBlocks) {
  __shared__ int lds[256];
  __shared__ int offs_s[5];
  __shared__ int tot_s[4];
  int t = threadIdx.x;
  int C = (nBlocks + 255) / 256;
  for (int r = 0; r < 4; ++r) {
    int s = 0;
    for (int b = t; b < nBlocks; b += 256) s += blockCnt[b * 4 + r];
    lds[t] = s;
    __syncthreads();
    for (int o = 128; o > 0; o >>= 1) {
      if (t < o) lds[t] += lds[t + o];
      __syncthreads();
    }
    if (t == 0) tot_s[r] = lds[0];
    __syncthreads();
  }
  if (t == 0) {
    int o = 0;
    offs_s[0] = 0;
    for (int r = 0; r < 4; ++r) { o += ((tot_s[r] + 63) >> 6) << 6; offs_s[r + 1] = o; }
    for (int r = 0; r < 5; ++r) offs[r] = offs_s[r];
  }
  __syncthreads();
  for (int r = 0; r < 4; ++r) {
    int b0 = t * C;
    int s = 0;
    for (int j = 0; j < C; ++j) {
      int b = b0 + j;
      if (b < nBlocks) s += blockCnt[b * 4 + r];
    }
    lds[t] = s;
    __syncthreads();
    int v = s;
    for (int o = 1; o < 256; o <<= 1) {
      int u = (t >= o) ? lds[t - o] : 0;
      __syncthreads();
      v += u;
      lds[t] = v;
      __syncthreads();
    }
    int run = offs_s[r] + (v - s);
    for (int j = 0; j < C; ++j) {
      int b = b0 + j;
      if (b < nBlocks) {
        blockBase[b * 4 + r] = run;
        run += blockCnt[b * 4 + r];
      }
    }
    __syncthreads();
  }
}

__global__ void scatter_kernel(const int* __restrict__ etype, const int* __restrict__ blockBase,
                               int* __restrict__ sorted, int E) {
  __shared__ int wcnt[4][4];
  int i = blockIdx.x * 256 + threadIdx.x;
  int rt = (i < E) ? etype[i] : -1;
  int wave = threadIdx.x >> 6, lane = threadIdx.x & 63;
  unsigned long long ltmask = (lane == 0) ? 0ull : (~0ull >> (64 - lane));
  int myrank = 0;
#pragma unroll
  for (int r = 0; r < 4; ++r) {
    unsigned long long m = __ballot(rt == r);
    if (lane == 0) wcnt[wave][r] = __popcll(m);
    if (rt == r) myrank = __popcll(m & ltmask);
  }
  __syncthreads();
  if (rt >= 0) {
    int wb = 0;
#pragma unroll
    for (int w = 0; w < 3; ++w) if (w < wave) wb += wcnt[w][rt];
    sorted[blockBase[blockIdx.x * 4 + rt] + wb + myrank] = i;
  }
}

// ---------- streaming MFMA GEMM, chunk-split across grid.z ----------
// A [M x 128] bf16; Bt [ldc x 128]; out [M x ldc] bf16. grid (Mtiles, sides, nsplit).
__global__ __launch_bounds__(256) void proj_multi_kernel(
    const __hip_bfloat16* __restrict__ A,
    const __hip_bfloat16* __restrict__ Bt0, const float* __restrict__ bias0,
    __hip_bfloat16* __restrict__ out0,
    const __hip_bfloat16* __restrict__ Bt1, const float* __restrict__ bias1,
    __hip_bfloat16* __restrict__ out1,
    int M, int ldc, int nchPer, int act)
{
  __shared__ __align__(16) short Bs[2][64 * 136];
  int side = blockIdx.y;
  const __hip_bfloat16* Bt = side ? Bt1 : Bt0;
  const float* bias = side ? bias1 : bias0;
  __hip_bfloat16* outp = side ? out1 : out0;
  int cb0 = blockIdx.z * nchPer;
  int tid = threadIdx.x;
  int rowBase = blockIdx.x * 128;
  int wid = tid >> 6, lane = tid & 63;
  int m16 = lane & 15, q = lane >> 4;

  // A fragments direct from global
  short8 af[4][2];
#pragma unroll
  for (int mi = 0; mi < 2; ++mi) {
    int row = rowBase + wid * 32 + mi * 16 + m16;
    const __hip_bfloat16* ap = A + (size_t)row * 128 + q * 8;
    bool ok = row < M;
#pragma unroll
    for (int ks = 0; ks < 4; ++ks) {
      if (ok) af[ks][mi] = *(const short8*)(const void*)(ap + ks * 32);
      else { short8 z; for (int t = 0; t < 8; ++t) z[t] = 0; af[ks][mi] = z; }
    }
  }

  // stage first chunk
#pragma unroll
  for (int t = 0; t < 4; ++t) {
    int c = tid + t * 256;
    int row = c >> 4, kk = (c & 15) << 3;
    *(short8*)(void*)(Bs[0] + row * 136 + kk) =
      *(const short8*)(const void*)(Bt + (size_t)(cb0 * 64 + row) * 128 + kk);
  }
  __syncthreads();

  int p = 0;
  for (int cb = cb0; cb < cb0 + nchPer; ++cb) {
    int colBase = cb * 64;
    f32x4 acc[2][4];
#pragma unroll
    for (int mi = 0; mi < 2; ++mi)
#pragma unroll
      for (int ni = 0; ni < 4; ++ni) {
        acc[mi][ni][0] = 0.f; acc[mi][ni][1] = 0.f;
        acc[mi][ni][2] = 0.f; acc[mi][ni][3] = 0.f;
      }
#pragma unroll
    for (int ks = 0; ks < 4; ++ks) {
      int kof = (ks << 5) + (q << 3);
      short8 bfr[4];
#pragma unroll
      for (int ni = 0; ni < 4; ++ni)
        bfr[ni] = *(const short8*)(const void*)(Bs[p] + (ni * 16 + m16) * 136 + kof);
#pragma unroll
      for (int mi = 0; mi < 2; ++mi)
#pragma unroll
        for (int ni = 0; ni < 4; ++ni)
          acc[mi][ni] = __builtin_amdgcn_mfma_f32_16x16x32_bf16(bfr[ni], af[ks][mi], acc[mi][ni], 0, 0, 0);
    }
    if (cb + 1 < cb0 + nchPer) {
#pragma unroll
      for (int t = 0; t < 4; ++t) {
        int c = tid + t * 256;
        int row = c >> 4, kk = (c & 15) << 3;
        *(short8*)(void*)(Bs[p ^ 1] + row * 136 + kk) =
          *(const short8*)(const void*)(Bt + (size_t)(colBase + 64 + row) * 128 + kk);
      }
    }
#pragma unroll
    for (int mi = 0; mi < 2; ++mi) {
      int row = rowBase + wid * 32 + mi * 16 + m16;
      if (row < M) {
#pragma unroll
        for (int ni = 0; ni < 4; ++ni) {
          int col0 = colBase + ni * 16 + q * 4;
          float4 b4 = *(const float4*)(bias + col0);
          float v0 = acc[mi][ni][0] + b4.x;
          float v1 = acc[mi][ni][1] + b4.y;
          float v2 = acc[mi][ni][2] + b4.z;
          float v3 = acc[mi][ni][3] + b4.w;
          if (act) {
            v0 = v0 / (1.f + __expf(-v0));
            v1 = v1 / (1.f + __expf(-v1));
            v2 = v2 / (1.f + __expf(-v2));
            v3 = v3 / (1.f + __expf(-v3));
          }
          __align__(8) __hip_bfloat16 tmp[4];
          tmp[0] = __float2bfloat16(v0);
          tmp[1] = __float2bfloat16(v1);
          tmp[2] = __float2bfloat16(v2);
          tmp[3] = __float2bfloat16(v3);
          *(uint2*)(void*)(outp + (size_t)row * ldc + col0) = *(const uint2*)(const void*)tmp;
        }
      }
    }
    __syncthreads();
    p ^= 1;
  }
}

// ---------- MFMA bf16 GEMM (FFN2): fp32 out, float4 stores ----------
__global__ __launch_bounds__(256) void mfma_gemm_kernel(
    const __hip_bfloat16* __restrict__ A,
    const __hip_bfloat16* __restrict__ Bt, const float* __restrict__ bias,
    float* __restrict__ Cout, int M, int K, int Ncols)
{
  __shared__ __align__(16) short Bs[64 * 136];
  int tid = threadIdx.x;
  int rowBase = blockIdx.y * 128, colBase = blockIdx.x * 64;
  int wid = tid >> 6, lane = tid & 63;
  int m16 = lane & 15, q = lane >> 4;

  f32x4 acc[2][4];
#pragma unroll
  for (int mi = 0; mi < 2; ++mi)
#pragma unroll
    for (int ni = 0; ni < 4; ++ni) {
      acc[mi][ni][0] = 0.f; acc[mi][ni][1] = 0.f;
      acc[mi][ni][2] = 0.f; acc[mi][ni][3] = 0.f;
    }

#pragma unroll 1
  for (int kc = 0; kc < K; kc += 128) {
#pragma unroll
    for (int t = 0; t < 4; ++t) {
      int c = tid + t * 256;
      int row = c >> 4, kk = (c & 15) << 3;
      *(short8*)(void*)(Bs + row * 136 + kk) =
        *(const short8*)(const void*)(Bt + (size_t)(colBase + row) * K + kc + kk);
    }
    __syncthreads();
    short8 af[4][2];
#pragma unroll
    for (int mi = 0; mi < 2; ++mi) {
      int row = rowBase + wid * 32 + mi * 16 + m16;
      const __hip_bfloat16* ap = A + (size_t)row * K + kc + q * 8;
      bool ok = row < M;
#pragma unroll
      for (int ks = 0; ks < 4; ++ks) {
        if (ok) af[ks][mi] = *(const short8*)(const void*)(ap + ks * 32);
        else { short8 z; for (int t2 = 0; t2 < 8; ++t2) z[t2] = 0; af[ks][mi] = z; }
      }
    }
#pragma unroll
    for (int ks = 0; ks < 4; ++ks) {
      int kof = (ks << 5) + (q << 3);
      short8 bfr[4];
#pragma unroll
      for (int ni = 0; ni < 4; ++ni)
        bfr[ni] = *(const short8*)(const void*)(Bs + (ni * 16 + m16) * 136 + kof);
#pragma unroll
      for (int mi = 0; mi < 2; ++mi)
#pragma unroll
        for (int ni = 0; ni < 4; ++ni)
          acc[mi][ni] = __builtin_amdgcn_mfma_f32_16x16x32_bf16(bfr[ni], af[ks][mi], acc[mi][ni], 0, 0, 0);
    }
    __syncthreads();
  }
#pragma unroll
  for (int mi = 0; mi < 2; ++mi) {
    int row = rowBase + wid * 32 + mi * 16 + m16;
    if (row < M) {
#pragma unroll
      for (int ni = 0; ni < 4; ++ni) {
        int col0 = colBase + ni * 16 + q * 4;
        float4 b4 = *(const float4*)(bias + col0);
        float4 v;
        v.x = acc[mi][ni][0] + b4.x;
        v.y = acc[mi][ni][1] + b4.y;
        v.z = acc[mi][ni][2] + b4.z;
        v.w = acc[mi][ni][3] + b4.w;
        *(float4*)(Cout + (size_t)row * Ncols + col0) = v;
      }
    }
  }
}

// ---------- per-edge score -> alpha + denom (relation r) ----------
__global__ __launch_bounds__(256) void score_kernel(
    const int* __restrict__ sorted, const int* __restrict__ offs, int r,
    const int* __restrict__ eidx, const float* __restrict__ eattr,
    const float* __restrict__ W_e, const float* __restrict__ att,
    const __hip_bfloat16* __restrict__ xlr, const __hip_bfloat16* __restrict__ xrr,
    float* __restrict__ alpha, float* __restrict__ denom, int N, int E)
{
  __shared__ float We_s[16 * 512];
  __shared__ float att_s[512];
  int tid = threadIdx.x;
#pragma unroll
  for (int t = 0; t < 32; ++t) {
    int idx = tid + (t << 8);
    We_s[idx] = W_e[((size_t)r * 24 + (idx >> 9)) * 512 + (idx & 511)];
  }
  att_s[tid]       = att[r * 512 + tid];
  att_s[tid + 256] = att[r * 512 + tid + 256];
  __syncthreads();

  int base = offs[r], end = offs[r + 1];
  int lane = tid & 63;
  int head = lane >> 4;
  int wave = (blockIdx.x << 2) + (tid >> 6);
  int nw = gridDim.x << 2;
  float4 atv0 = *(const float4*)(att_s + lane * 8);
  float4 atv1 = *(const float4*)(att_s + lane * 8 + 4);

  for (int i = base + wave; i < end; i += nw) {
    int eid = sorted[i];
    if (eid < 0) continue;
    int src = eidx[eid], dst = eidx[E + eid];
    float4 a0 = *(const float4*)(eattr + (size_t)eid * 16);
    float4 a1 = *(const float4*)(eattr + (size_t)eid * 16 + 4);
    float4 a2 = *(const float4*)(eattr + (size_t)eid * 16 + 8);
    float4 a3 = *(const float4*)(eattr + (size_t)eid * 16 + 12);
    float4 lv = *(const float4*)(const void*)(xlr + (size_t)src * 512 + lane * 8);
    float4 rv = *(const float4*)(const void*)(xrr + (size_t)dst * 512 + lane * 8);
    const unsigned* lw = (const unsigned*)&lv;
    const unsigned* rw = (const unsigned*)&rv;
    float x[8];
#pragma unroll
    for (int j = 0; j < 4; ++j) {
      x[2*j]   = __uint_as_float(lw[j] << 16)         + __uint_as_float(rw[j] << 16);
      x[2*j+1] = __uint_as_float(lw[j] & 0xffff0000u) + __uint_as_float(rw[j] & 0xffff0000u);
    }
    float aa[16] = {a0.x,a0.y,a0.z,a0.w, a1.x,a1.y,a1.z,a1.w,
                    a2.x,a2.y,a2.z,a2.w, a3.x,a3.y,a3.z,a3.w};
    float ef[8] = {0.f,0.f,0.f,0.f,0.f,0.f,0.f,0.f};
#pragma unroll
    for (int k = 0; k < 16; ++k) {
      float4 w0 = *(const float4*)(We_s + k * 512 + lane * 8);
      float4 w1 = *(const float4*)(We_s + k * 512 + lane * 8 + 4);
      ef[0] += aa[k]*w0.x; ef[1] += aa[k]*w0.y; ef[2] += aa[k]*w0.z; ef[3] += aa[k]*w0.w;
      ef[4] += aa[k]*w1.x; ef[5] += aa[k]*w1.y; ef[6] += aa[k]*w1.z; ef[7] += aa[k]*w1.w;
    }
    const float* at = (const float*)&atv0;
    float s = 0.f;
#pragma unroll
    for (int j = 0; j < 8; ++j) {
      float xv = x[j] + ef[j];
      xv = (xv > 0.f) ? xv : NEG * xv;
      s += xv * ((j < 4) ? at[j] : ((const float*)&atv1)[j - 4]);
    }
    s += __shfl_xor(s, 1);
    s += __shfl_xor(s, 2);
    s += __shfl_xor(s, 4);
    s += __shfl_xor(s, 8);
    if ((lane & 15) == 0) {
      float al = __expf(s);
      alpha[(size_t)eid * 4 + head] = al;
      atomicAdd(&denom[((size_t)r * N + dst) * 4 + head], al);
    }
  }
}

// ---------- aggregate (relation r) ----------
__global__ __launch_bounds__(256) void agg_kernel(
    const int* __restrict__ sorted, const int* __restrict__ offs, int r,
    const int* __restrict__ eidx, const float* __restrict__ alpha,
    const float* __restrict__ denom, const __hip_bfloat16* __restrict__ xlr,
    const float* __restrict__ gw, float* __restrict__ hmsg, int N, int E)
{
  int base = offs[r], end = offs[r + 1];
  float g = 0.25f * gw[r];
  int lane = threadIdx.x & 63;
  int wave = (blockIdx.x << 2) + (threadIdx.x >> 6);
  int nw = gridDim.x << 2;
  int col = lane * 2;
  for (int i = base + wave; i < end; i += nw) {
    int eid = sorted[i];
    if (eid < 0) continue;
    int src = eidx[eid], dst = eidx[E + eid];
    float4 al = *(const float4*)(alpha + (size_t)eid * 4);
    float4 dn = *(const float4*)(denom + ((size_t)r * N + dst) * 4);
    float coef[4] = {g * al.x / dn.x, g * al.y / dn.y, g * al.z / dn.z, g * al.w / dn.w};
    float s0 = 0.f, s1 = 0.f;
#pragma unroll
    for (int hh = 0; hh < 4; ++hh) {
      unsigned pw = *(const unsigned*)(const void*)(xlr + (size_t)src * 512 + hh * 128 + col);
      s0 += coef[hh] * __uint_as_float(pw << 16);
      s1 += coef[hh] * __uint_as_float(pw & 0xffff0000u);
    }
    atomicAdd(&hmsg[(size_t)dst * 128 + col],     s0);
    atomicAdd(&hmsg[(size_t)dst * 128 + col + 1], s1);
  }
}

// ---------- layernorm over 128 ----------
__global__ __launch_bounds__(256) void ln_kernel(
    const float* __restrict__ X, const float* __restrict__ Y,
    const float* __restrict__ g, const float* __restrict__ b,
    float* __restrict__ out, __hip_bfloat16* __restrict__ outbf, int N)
{
  int w = (int)((blockIdx.x * (unsigned)blockDim.x + threadIdx.x) >> 6);
  int lane = threadIdx.x & 63;
  if (w >= N) return;
  int c = lane * 2;
  float2 xv = *(const float2*)(X + (size_t)w * 128 + c);
  float2 yv = *(const float2*)(Y + (size_t)w * 128 + c);
  float v0 = xv.x + yv.x, v1 = xv.y + yv.y;
  float s1 = v0 + v1, s2 = v0 * v0 + v1 * v1;
#pragma unroll
  for (int off = 1; off < 64; off <<= 1) {
    s1 += __shfl_xor(s1, off);
    s2 += __shfl_xor(s2, off);
  }
  float mu = s1 * (1.f / 128.f);
  float var = s2 * (1.f / 128.f) - mu * mu;
  float rstd = rsqrtf(var + EPSLN);
  float o0 = (v0 - mu) * rstd * g[c]     + b[c];
  float o1 = (v1 - mu) * rstd * g[c + 1] + b[c + 1];
  out[(size_t)w * 128 + c]     = o0;
  out[(size_t)w * 128 + c + 1] = o1;
  if (outbf) {
    outbf[(size_t)w * 128 + c]     = __float2bfloat16(o0);
    outbf[(size_t)w * 128 + c + 1] = __float2bfloat16(o1);
  }
}

extern "C" void kernel_launch(void* const* d_in, const int* in_sizes, int n_in,
                              void* d_out, int out_size, void* d_ws, size_t ws_size,
                              hipStream_t stream) {
  const float* h       = (const float*)d_in[0];
  const int*   eidx    = (const int*)d_in[1];
  const float* eattr   = (const float*)d_in[2];
  const int*   etype   = (const int*)d_in[3];
  const float* rel_emb = (const float*)d_in[4];
  const float* W_l     = (const float*)d_in[5];
  const float* b_l     = (const float*)d_in[6];
  const float* W_r     = (const float*)d_in[7];
  const float* b_r     = (const float*)d_in[8];
  const float* W_e     = (const float*)d_in[9];
  const float* att     = (const float*)d_in[10];
  const float* bias    = (const float*)d_in[11];
  const float* gate    = (const float*)d_in[12];
  const float* g1      = (const float*)d_in[13];
  const float* bt1     = (const float*)d_in[14];
  const float* g2      = (const float*)d_in[15];
  const float* bt2     = (const float*)d_in[16];
  const float* Wf1     = (const float*)d_in[17];
  const float* bf1     = (const float*)d_in[18];
  const float* Wf2     = (const float*)d_in[19];
  const float* bf2     = (const float*)d_in[20];

  const int N = in_sizes[0] / NF;     // 40000
  const int E = in_sizes[3];          // 150000
  const int nTiles = (E + 4 * 63 + 63) / 64;
  const int sortedN = nTiles * 64;
  const int Mtiles = (N + 127) / 128;
  const int histBlocks = (E + 255) / 256;

  // workspace carve (~120 MB peak, ws = 256 MiB)
  char* ws = (char*)d_ws;
  size_t off = 0;
  auto carve = [&](size_t bytes) -> void* {
    void* p = ws + off;
    off = (off + bytes + 255) & ~(size_t)255;
    return p;
  };
  __hip_bfloat16* xl_r  = (__hip_bfloat16*)carve((size_t)N * 512 * 2);
  __hip_bfloat16* xr_r  = (__hip_bfloat16*)carve((size_t)N * 512 * 2);
  __hip_bfloat16* hbf   = (__hip_bfloat16*)carve((size_t)N * 128 * 2);
  __hip_bfloat16* Wlt   = (__hip_bfloat16*)carve((size_t)4 * 512 * 128 * 2);
  __hip_bfloat16* Wrt   = (__hip_bfloat16*)carve((size_t)4 * 512 * 128 * 2);
  __hip_bfloat16* Wf1t  = (__hip_bfloat16*)carve((size_t)256 * 128 * 2);
  __hip_bfloat16* Wf2t  = (__hip_bfloat16*)carve((size_t)128 * 256 * 2);
  float*    bias_c = (float*)carve((size_t)4 * 512 * 4);
  float*    alpha  = (float*)carve((size_t)E * 4 * 4);
  float*    denom  = (float*)carve((size_t)4 * N * 4 * 4);
  float*    hmsg   = (float*)carve((size_t)N * 128 * 4);
  int*      sorted = (int*)carve((size_t)sortedN * 4);
  int*      blockCnt  = (int*)carve((size_t)histBlocks * 4 * 4);
  int*      blockBase = (int*)carve((size_t)histBlocks * 4 * 4);
  int*      offsb  = (int*)carve(64);
  float*    gw     = (float*)carve(256);
  // FFN overlays onto xl_r/xr_r (dead after relation loop)
  float*          h1   = (float*)(ws + 0);
  __hip_bfloat16* h1bf = (__hip_bfloat16*)(ws + (size_t)N * 128 * 4);
  __hip_bfloat16* uffn = (__hip_bfloat16*)(ws + (size_t)N * 128 * 6);
  float*          yffn = (float*)(ws + (size_t)N * 128 * 6 + (size_t)N * 256 * 2);
  float*          out  = (float*)d_out;

  // fused prep (replaces 8 tiny kernels)
  prep_all_kernel<<<1024, 256, 0, stream>>>(
      h, hbf, W_l, Wlt, W_r, Wrt, Wf1, Wf1t, Wf2, Wf2t,
      b_r, rel_emb, W_e, bias_c, gate, gw, bias, hmsg, denom, sorted, N, sortedN);
  // atomic-free counting sort
  blockhist_kernel<<<histBlocks, 256, 0, stream>>>(etype, blockCnt, E);
  scan_kernel<<<1, 256, 0, stream>>>(blockCnt, blockBase, offsb, histBlocks);
  scatter_kernel<<<histBlocks, 256, 0, stream>>>(etype, blockBase, sorted, E);

  // per-relation: proj (xl_r, xr_r) -> score/alpha/denom -> aggregate
  for (int r = 0; r < 4; ++r) {
    proj_multi_kernel<<<dim3(Mtiles, 2, 2), 256, 0, stream>>>(
        hbf,
        Wlt + (size_t)r * 512 * 128, b_l + r * 512, xl_r,
        Wrt + (size_t)r * 512 * 128, bias_c + r * 512, xr_r,
        N, 512, 4, 0);
    score_kernel<<<1024, 256, 0, stream>>>(sorted, offsb, r, eidx, eattr, W_e, att,
                                           xl_r, xr_r, alpha, denom, N, E);
    agg_kernel<<<1024, 256, 0, stream>>>(sorted, offsb, r, eidx, alpha, denom,
                                         xl_r, gw, hmsg, N, E);
  }

  // h1 = LN(h + hmsg); also bf16 copy for FFN
  ln_kernel<<<(N + 3) / 4, 256, 0, stream>>>(h, hmsg, g1, bt1, h1, h1bf, N);
  // u = silu(h1 @ Wf1 + bf1)
  proj_multi_kernel<<<dim3(Mtiles, 1, 2), 256, 0, stream>>>(
      h1bf, Wf1t, bf1, uffn, Wf1t, bf1, uffn, N, 256, 2, 1);
  // y = u @ Wf2 + bf2
  mfma_gemm_kernel<<<dim3(NF / 64, Mtiles), 256, 0, stream>>>(
      uffn, Wf2t, bf2, yffn, N, 256, NF);
  // out = LN(h1 + y)
  ln_kernel<<<(N + 3) / 4, 256, 0, stream>>>(h1, yffn, g2, bt2, out, nullptr, N);
}